// Round 1
// baseline (422.278 us; speedup 1.0000x reference)
//
#include <hip/hip_runtime.h>
#include <hip/hip_bf16.h>

#define NTOT 8192
#define FIN 128
#define FOUT 32
#define NH 4

typedef __attribute__((ext_vector_type(4))) float f32x4;
typedef __attribute__((ext_vector_type(4))) int i32x4;
typedef __attribute__((ext_vector_type(8))) __bf16 bf16x8;

__device__ __forceinline__ unsigned short f2bf(float x) {
  __hip_bfloat16 h = __float2bfloat16(x);
  return *reinterpret_cast<unsigned short*>(&h);
}

// ---------------- k1: h = X @ W  (einsum nf,hfo->hno), stored as
//   h   [N][128] f32   (col = hd*32+o)  -- for k2
//   hT  [128][N] bf16  (row = hd*32+o)  -- B-operand source for k3
__global__ __launch_bounds__(256, 1) void k1_project(
    const float* __restrict__ X, const float* __restrict__ W,
    float* __restrict__ h, unsigned short* __restrict__ hT) {
  __shared__ float Xs[64 * 128];  // 32 KB
  __shared__ float Ws[32 * 128];  // 16 KB (one K-phase)
  int t = threadIdx.x;
  int nb = blockIdx.x * 64;

  const f32x4* Xg = reinterpret_cast<const f32x4*>(X + (size_t)nb * FIN);
  f32x4* Xs4 = reinterpret_cast<f32x4*>(Xs);
#pragma unroll
  for (int r = 0; r < 8; ++r) Xs4[t + r * 256] = Xg[t + r * 256];

  int ng = t >> 5, oq = t & 31;
  int n0 = ng * 8, o0 = oq * 4;
  f32x4 acc[8];
#pragma unroll
  for (int nn = 0; nn < 8; ++nn) acc[nn] = (f32x4){0.f, 0.f, 0.f, 0.f};

  for (int kp = 0; kp < 4; ++kp) {
    __syncthreads();
    // stage W[k in kp*32..+31] as Ws[kk][c], c = hd*32+o
#pragma unroll
    for (int r = 0; r < 4; ++r) {
      int q = t + r * 256;  // float4 id, 1024 total
      int flat = q * 4;
      int kk = flat >> 7;
      int c = flat & 127;
      int hdd = c >> 5;
      int oo = c & 31;
      f32x4 v = *reinterpret_cast<const f32x4*>(
          W + hdd * (FIN * FOUT) + (kp * 32 + kk) * FOUT + oo);
      *reinterpret_cast<f32x4*>(&Ws[kk * 128 + c]) = v;
    }
    __syncthreads();
#pragma unroll 8
    for (int kk = 0; kk < 32; ++kk) {
      f32x4 wv = *reinterpret_cast<const f32x4*>(&Ws[kk * 128 + o0]);
#pragma unroll
      for (int nn = 0; nn < 8; ++nn) {
        float xv = Xs[(n0 + nn) * 128 + kp * 32 + kk];
        acc[nn] += xv * wv;
      }
    }
  }
#pragma unroll
  for (int nn = 0; nn < 8; ++nn) {
    size_t n = nb + n0 + nn;
    *reinterpret_cast<f32x4*>(&h[n * 128 + o0]) = acc[nn];
#pragma unroll
    for (int c = 0; c < 4; ++c)
      hT[(size_t)(o0 + c) * NTOT + n] = f2bf(acc[nn][c]);
  }
}

// ---------------- k2: per-node scores + separable-exp tables
// SD layout: [arr][hd][N], arr: 0=s 1=exp(s) 2=exp(.2s) 3=d 4=exp(d) 5=exp(.2d)
__global__ __launch_bounds__(256, 1) void k2_scores(
    const float* __restrict__ h, const float* __restrict__ a_src,
    const float* __restrict__ a_dst, float* __restrict__ SD) {
  int n = blockIdx.x * 256 + threadIdx.x;
  const f32x4* hv = reinterpret_cast<const f32x4*>(h + (size_t)n * 128);
  const f32x4* as4 = reinterpret_cast<const f32x4*>(a_src);
  const f32x4* ad4 = reinterpret_cast<const f32x4*>(a_dst);
#pragma unroll
  for (int hd = 0; hd < NH; ++hd) {
    f32x4 sa = {0.f, 0.f, 0.f, 0.f}, da = {0.f, 0.f, 0.f, 0.f};
#pragma unroll
    for (int q = 0; q < 8; ++q) {
      f32x4 x = hv[hd * 8 + q];
      sa += x * as4[hd * 8 + q];
      da += x * ad4[hd * 8 + q];
    }
    float s = sa[0] + sa[1] + sa[2] + sa[3];
    float d = da[0] + da[1] + da[2] + da[3];
    SD[(0 * NH + hd) * NTOT + n] = s;
    SD[(1 * NH + hd) * NTOT + n] = expf(s);
    SD[(2 * NH + hd) * NTOT + n] = expf(0.2f * s);
    SD[(3 * NH + hd) * NTOT + n] = d;
    SD[(4 * NH + hd) * NTOT + n] = expf(d);
    SD[(5 * NH + hd) * NTOT + n] = expf(0.2f * d);
  }
}

// ---------------- k3: fused masked softmax + PV via MFMA
// block = 32 rows, 8 waves; wave w: head = w&3, row-half = w>>2 (16 rows).
// Per j-tile (32): lane builds A-frag of P in-register (m=l&15, k=(l>>4)*8+e),
// loads B-frags straight from global hT (L2-resident), 2 MFMAs.
// exp(LeakyReLU(s+d)) = (s+d>=0) ? exp(s)exp(d) : exp(.2s)exp(.2d)  (separable)
__global__ __launch_bounds__(512, 1) void k3_attn(
    const int* __restrict__ adj, const float* __restrict__ SD,
    const unsigned short* __restrict__ hTbits, float* __restrict__ out) {
  const int N = NTOT;
  int t = threadIdx.x;
  int w = t >> 6;
  int l = t & 63;
  int hd = w & 3;
  int isub = w >> 2;
  int ibase = blockIdx.x * 32 + isub * 16;
  int m = l & 15;
  int i = ibase + m;
  int jc = (l >> 4) * 8;

  float sv = SD[(0 * NH + hd) * N + i];
  float E1 = SD[(1 * NH + hd) * N + i];
  float E2 = SD[(2 * NH + hd) * N + i];
  const float* dptr = SD + (3 * NH + hd) * N;
  const float* f1p = SD + (4 * NH + hd) * N;
  const float* f2p = SD + (5 * NH + hd) * N;
  const int* adjrow = adj + (size_t)i * N;
  const __bf16* hT0 =
      reinterpret_cast<const __bf16*>(hTbits) + (size_t)(hd * FOUT + m) * N;
  const __bf16* hT1 = hT0 + (size_t)16 * N;

  f32x4 acc0 = {0.f, 0.f, 0.f, 0.f}, acc1 = {0.f, 0.f, 0.f, 0.f};
  float lacc = 0.f;

#pragma unroll 2
  for (int jb = 0; jb < N; jb += 32) {
    int jj = jb + jc;
    i32x4 av0 = *reinterpret_cast<const i32x4*>(adjrow + jj);
    i32x4 av1 = *reinterpret_cast<const i32x4*>(adjrow + jj + 4);
    f32x4 dv0 = *reinterpret_cast<const f32x4*>(dptr + jj);
    f32x4 dv1 = *reinterpret_cast<const f32x4*>(dptr + jj + 4);
    f32x4 g10 = *reinterpret_cast<const f32x4*>(f1p + jj);
    f32x4 g11 = *reinterpret_cast<const f32x4*>(f1p + jj + 4);
    f32x4 g20 = *reinterpret_cast<const f32x4*>(f2p + jj);
    f32x4 g21 = *reinterpret_cast<const f32x4*>(f2p + jj + 4);
    bf16x8 b0 = *reinterpret_cast<const bf16x8*>(hT0 + jj);
    bf16x8 b1 = *reinterpret_cast<const bf16x8*>(hT1 + jj);
    bf16x8 af;
#pragma unroll
    for (int e = 0; e < 4; ++e) {
      float x = sv + dv0[e];
      float p = (x >= 0.f) ? (E1 * g10[e]) : (E2 * g20[e]);
      p = (av0[e] != 0) ? p : 0.f;
      lacc += p;
      af[e] = (__bf16)p;
    }
#pragma unroll
    for (int e = 0; e < 4; ++e) {
      float x = sv + dv1[e];
      float p = (x >= 0.f) ? (E1 * g11[e]) : (E2 * g21[e]);
      p = (av1[e] != 0) ? p : 0.f;
      lacc += p;
      af[e + 4] = (__bf16)p;
    }
    acc0 = __builtin_amdgcn_mfma_f32_16x16x32_bf16(af, b0, acc0, 0, 0, 0);
    acc1 = __builtin_amdgcn_mfma_f32_16x16x32_bf16(af, b1, acc1, 0, 0, 0);
  }

  // row-sum l: combine the 4 j-chunk groups (lanes sharing l&15)
  lacc += __shfl_xor(lacc, 16);
  lacc += __shfl_xor(lacc, 32);

  // epilogue: D layout col=lane&15, row=(lane>>4)*4+reg (m89-verified)
#pragma unroll
  for (int half = 0; half < 2; ++half) {
    f32x4 a = half ? acc1 : acc0;
#pragma unroll
    for (int r = 0; r < 4; ++r) {
      int row = ((l >> 4) << 2) + r;
      float lr = __shfl(lacc, row);  // lane 'row' holds l for row 'row'
      float invl = (lr > 0.f) ? (1.f / lr) : 0.f;
      out[(size_t)(ibase + row) * (NH * FOUT) + hd * FOUT + half * 16 +
          (l & 15)] = a[r] * invl;
    }
  }
}

extern "C" void kernel_launch(void* const* d_in, const int* in_sizes, int n_in,
                              void* d_out, int out_size, void* d_ws,
                              size_t ws_size, hipStream_t stream) {
  const float* X = (const float*)d_in[0];
  const int* adj = (const int*)d_in[1];
  const float* W = (const float*)d_in[2];
  const float* a_src = (const float*)d_in[3];
  const float* a_dst = (const float*)d_in[4];
  float* out = (float*)d_out;

  char* ws = (char*)d_ws;
  float* h = (float*)ws;                                  // 4 MB
  unsigned short* hT = (unsigned short*)(ws + 4194304);   // 2 MB
  float* SD = (float*)(ws + 4194304 + 2097152);           // 768 KB

  k1_project<<<dim3(128), dim3(256), 0, stream>>>(X, W, h, hT);
  k2_scores<<<dim3(32), dim3(256), 0, stream>>>(h, a_src, a_dst, SD);
  k3_attn<<<dim3(256), dim3(512), 0, stream>>>(adj, SD, hT, out);
}

// Round 2
// 321.939 us; speedup vs baseline: 1.3117x; 1.3117x over previous
//
#include <hip/hip_runtime.h>
#include <hip/hip_bf16.h>

#define NTOT 8192
#define FIN 128
#define FOUT 32
#define NH 4
#define NSEG 4
#define SEGJ (NTOT / NSEG)  // 2048

typedef __attribute__((ext_vector_type(4))) float f32x4;
typedef __attribute__((ext_vector_type(4))) int i32x4;
typedef __attribute__((ext_vector_type(8))) __bf16 bf16x8;

__device__ __forceinline__ unsigned short f2bf(float x) {
  __hip_bfloat16 h = __float2bfloat16(x);
  return *reinterpret_cast<unsigned short*>(&h);
}

// ---------------- k0: bit-pack adj (streaming, coalesced).
// bitsT[jw][i] = bits for cols jw*32..jw*32+31 of row i.  8 MB total.
__global__ __launch_bounds__(512, 1) void k0_pack(
    const int* __restrict__ adj, unsigned int* __restrict__ bitsT) {
  int wave = (blockIdx.x * 512 + threadIdx.x) >> 6;  // 8192 waves
  int l = threadIdx.x & 63;
  const int NW = 8192;
  const int NT = NTOT * (NTOT / 64);  // 1,048,576 wave-tasks
  for (int task = wave; task < NT; task += NW) {
    int row = task & (NTOT - 1);
    int j64 = task >> 13;
    int v = adj[(size_t)row * NTOT + j64 * 64 + l];
    unsigned long long m = __ballot(v != 0);
    if (l == 0) {
      bitsT[(size_t)(2 * j64) * NTOT + row] = (unsigned int)m;
      bitsT[(size_t)(2 * j64 + 1) * NTOT + row] = (unsigned int)(m >> 32);
    }
  }
}

// ---------------- k1: h = X @ W, stored as h [N][128] f32 and hT [128][N] bf16
__global__ __launch_bounds__(256, 1) void k1_project(
    const float* __restrict__ X, const float* __restrict__ W,
    float* __restrict__ h, unsigned short* __restrict__ hT) {
  __shared__ float Xs[64 * 128];
  __shared__ float Ws[32 * 128];
  int t = threadIdx.x;
  int nb = blockIdx.x * 64;

  const f32x4* Xg = reinterpret_cast<const f32x4*>(X + (size_t)nb * FIN);
  f32x4* Xs4 = reinterpret_cast<f32x4*>(Xs);
#pragma unroll
  for (int r = 0; r < 8; ++r) Xs4[t + r * 256] = Xg[t + r * 256];

  int ng = t >> 5, oq = t & 31;
  int n0 = ng * 8, o0 = oq * 4;
  f32x4 acc[8];
#pragma unroll
  for (int nn = 0; nn < 8; ++nn) acc[nn] = (f32x4){0.f, 0.f, 0.f, 0.f};

  for (int kp = 0; kp < 4; ++kp) {
    __syncthreads();
#pragma unroll
    for (int r = 0; r < 4; ++r) {
      int q = t + r * 256;
      int flat = q * 4;
      int kk = flat >> 7;
      int c = flat & 127;
      int hdd = c >> 5;
      int oo = c & 31;
      f32x4 v = *reinterpret_cast<const f32x4*>(
          W + hdd * (FIN * FOUT) + (kp * 32 + kk) * FOUT + oo);
      *reinterpret_cast<f32x4*>(&Ws[kk * 128 + c]) = v;
    }
    __syncthreads();
#pragma unroll 8
    for (int kk = 0; kk < 32; ++kk) {
      f32x4 wv = *reinterpret_cast<const f32x4*>(&Ws[kk * 128 + o0]);
#pragma unroll
      for (int nn = 0; nn < 8; ++nn) {
        float xv = Xs[(n0 + nn) * 128 + kp * 32 + kk];
        acc[nn] += xv * wv;
      }
    }
  }
#pragma unroll
  for (int nn = 0; nn < 8; ++nn) {
    size_t n = nb + n0 + nn;
    *reinterpret_cast<f32x4*>(&h[n * 128 + o0]) = acc[nn];
#pragma unroll
    for (int c = 0; c < 4; ++c)
      hT[(size_t)(o0 + c) * NTOT + n] = f2bf(acc[nn][c]);
  }
}

// ---------------- k2: per-node scores + separable-exp tables
// SD layout: [arr][hd][N], arr: 0=s 1=exp(s) 2=exp(.2s) 3=d 4=exp(d) 5=exp(.2d)
__global__ __launch_bounds__(256, 1) void k2_scores(
    const float* __restrict__ h, const float* __restrict__ a_src,
    const float* __restrict__ a_dst, float* __restrict__ SD) {
  int n = blockIdx.x * 256 + threadIdx.x;
  const f32x4* hv = reinterpret_cast<const f32x4*>(h + (size_t)n * 128);
  const f32x4* as4 = reinterpret_cast<const f32x4*>(a_src);
  const f32x4* ad4 = reinterpret_cast<const f32x4*>(a_dst);
#pragma unroll
  for (int hd = 0; hd < NH; ++hd) {
    f32x4 sa = {0.f, 0.f, 0.f, 0.f}, da = {0.f, 0.f, 0.f, 0.f};
#pragma unroll
    for (int q = 0; q < 8; ++q) {
      f32x4 x = hv[hd * 8 + q];
      sa += x * as4[hd * 8 + q];
      da += x * ad4[hd * 8 + q];
    }
    float s = sa[0] + sa[1] + sa[2] + sa[3];
    float d = da[0] + da[1] + da[2] + da[3];
    SD[(0 * NH + hd) * NTOT + n] = s;
    SD[(1 * NH + hd) * NTOT + n] = expf(s);
    SD[(2 * NH + hd) * NTOT + n] = expf(0.2f * s);
    SD[(3 * NH + hd) * NTOT + n] = d;
    SD[(4 * NH + hd) * NTOT + n] = expf(d);
    SD[(5 * NH + hd) * NTOT + n] = expf(0.2f * d);
  }
}

// ---------------- k3: fused masked softmax + PV via MFMA, split-K over j.
// blockIdx: itile = bx>>2 (32 rows), seg = bx&3 (2048 cols).
// 8 waves: head = w&3, row-half = w>>2. Writes partial acc + row-sums.
__global__ __launch_bounds__(512, 8) void k3_attn(
    const unsigned int* __restrict__ bitsT, const float* __restrict__ SD,
    const unsigned short* __restrict__ hTbits, float* __restrict__ pacc,
    float* __restrict__ plsum) {
  const int N = NTOT;
  int t = threadIdx.x;
  int w = t >> 6;
  int l = t & 63;
  int hd = w & 3;
  int isub = w >> 2;
  int itile = blockIdx.x >> 2;
  int seg = blockIdx.x & 3;
  int ibase = itile * 32 + isub * 16;
  int m = l & 15;
  int i = ibase + m;
  int jc = (l >> 4) * 8;

  float sv = SD[(0 * NH + hd) * N + i];
  float E1 = SD[(1 * NH + hd) * N + i];
  float E2 = SD[(2 * NH + hd) * N + i];
  const float* dptr = SD + (3 * NH + hd) * N;
  const float* f1p = SD + (4 * NH + hd) * N;
  const float* f2p = SD + (5 * NH + hd) * N;
  const __bf16* hT0 =
      reinterpret_cast<const __bf16*>(hTbits) + (size_t)(hd * FOUT + m) * N;
  const __bf16* hT1 = hT0 + (size_t)16 * N;

  f32x4 acc0 = {0.f, 0.f, 0.f, 0.f}, acc1 = {0.f, 0.f, 0.f, 0.f};
  float lacc = 0.f;

  int jend = (seg + 1) * SEGJ;
#pragma unroll 2
  for (int jb = seg * SEGJ; jb < jend; jb += 32) {
    int jj = jb + jc;
    unsigned int wsh = bitsT[(size_t)(jb >> 5) * N + i] >> jc;
    f32x4 dv0 = *reinterpret_cast<const f32x4*>(dptr + jj);
    f32x4 dv1 = *reinterpret_cast<const f32x4*>(dptr + jj + 4);
    f32x4 g10 = *reinterpret_cast<const f32x4*>(f1p + jj);
    f32x4 g11 = *reinterpret_cast<const f32x4*>(f1p + jj + 4);
    f32x4 g20 = *reinterpret_cast<const f32x4*>(f2p + jj);
    f32x4 g21 = *reinterpret_cast<const f32x4*>(f2p + jj + 4);
    bf16x8 b0 = *reinterpret_cast<const bf16x8*>(hT0 + jj);
    bf16x8 b1 = *reinterpret_cast<const bf16x8*>(hT1 + jj);
    bf16x8 af;
#pragma unroll
    for (int e = 0; e < 4; ++e) {
      float x = sv + dv0[e];
      float p = (x >= 0.f) ? (E1 * g10[e]) : (E2 * g20[e]);
      p = ((wsh >> e) & 1u) ? p : 0.f;
      lacc += p;
      af[e] = (__bf16)p;
    }
#pragma unroll
    for (int e = 0; e < 4; ++e) {
      float x = sv + dv1[e];
      float p = (x >= 0.f) ? (E1 * g11[e]) : (E2 * g21[e]);
      p = ((wsh >> (e + 4)) & 1u) ? p : 0.f;
      lacc += p;
      af[e + 4] = (__bf16)p;
    }
    acc0 = __builtin_amdgcn_mfma_f32_16x16x32_bf16(af, b0, acc0, 0, 0, 0);
    acc1 = __builtin_amdgcn_mfma_f32_16x16x32_bf16(af, b1, acc1, 0, 0, 0);
  }

  // full row-sum for this segment: combine the 4 j-chunk lane groups
  lacc += __shfl_xor(lacc, 16);
  lacc += __shfl_xor(lacc, 32);
  if (l < 16) plsum[(seg * NH + hd) * N + ibase + l] = lacc;

  // D layout: col=lane&15, row=(lane>>4)*4+reg (m89-verified)
#pragma unroll
  for (int half = 0; half < 2; ++half) {
    f32x4 a = half ? acc1 : acc0;
#pragma unroll
    for (int r = 0; r < 4; ++r) {
      int row = ((l >> 4) << 2) + r;
      pacc[((size_t)seg * N + ibase + row) * (NH * FOUT) + hd * FOUT +
           half * 16 + (l & 15)] = a[r];
    }
  }
}

// ---------------- k4: combine segments + normalize
__global__ __launch_bounds__(256, 1) void k4_combine(
    const float* __restrict__ pacc, const float* __restrict__ plsum,
    float* __restrict__ out) {
  int idx = blockIdx.x * 256 + threadIdx.x;  // 0 .. N*128-1
  int i = idx >> 7;
  int c = idx & 127;
  int hd = c >> 5;
  float a = 0.f, ls = 0.f;
#pragma unroll
  for (int s = 0; s < NSEG; ++s) {
    a += pacc[((size_t)s * NTOT + i) * 128 + c];
    ls += plsum[(s * NH + hd) * NTOT + i];
  }
  out[idx] = (ls > 0.f) ? a / ls : 0.f;
}

extern "C" void kernel_launch(void* const* d_in, const int* in_sizes, int n_in,
                              void* d_out, int out_size, void* d_ws,
                              size_t ws_size, hipStream_t stream) {
  const float* X = (const float*)d_in[0];
  const int* adj = (const int*)d_in[1];
  const float* W = (const float*)d_in[2];
  const float* a_src = (const float*)d_in[3];
  const float* a_dst = (const float*)d_in[4];
  float* out = (float*)d_out;

  char* ws = (char*)d_ws;
  float* h = (float*)ws;                                   // 4 MB
  unsigned short* hT = (unsigned short*)(ws + 4194304);    // 2 MB
  float* SD = (float*)(ws + 6291456);                      // 768 KB
  unsigned int* bitsT = (unsigned int*)(ws + 7077888);     // 8 MB
  float* pacc = (float*)(ws + 15466496);                   // 16 MB
  float* plsum = (float*)(ws + 32243712);                  // 512 KB

  k0_pack<<<dim3(1024), dim3(512), 0, stream>>>(adj, bitsT);
  k1_project<<<dim3(128), dim3(256), 0, stream>>>(X, W, h, hT);
  k2_scores<<<dim3(32), dim3(256), 0, stream>>>(h, a_src, a_dst, SD);
  k3_attn<<<dim3(256 * NSEG), dim3(512), 0, stream>>>(bitsT, SD, hT, pacc,
                                                      plsum);
  k4_combine<<<dim3(4096), dim3(256), 0, stream>>>(pacc, plsum, out);
}

// Round 3
// 269.455 us; speedup vs baseline: 1.5672x; 1.1948x over previous
//
#include <hip/hip_runtime.h>
#include <hip/hip_bf16.h>

#define NTOT 8192
#define FIN 128
#define FOUT 32
#define NH 4
#define NSEG 4
#define SEGJ (NTOT / NSEG)  // 2048
#define LOG2E 1.4426950408889634f

typedef __attribute__((ext_vector_type(4))) float f32x4;
typedef __attribute__((ext_vector_type(4))) int i32x4;
typedef __attribute__((ext_vector_type(8))) __bf16 bf16x8;
typedef unsigned long long u64;
typedef unsigned int u32;

__device__ __forceinline__ unsigned short f2bf(float x) {
  __hip_bfloat16 h = __float2bfloat16(x);
  return *reinterpret_cast<unsigned short*>(&h);
}

// ---------------- k0: bit-pack adj, row-major bits: bitsR[i][jw] (8 MB)
__global__ __launch_bounds__(512, 2) void k0_pack(
    const int* __restrict__ adj, u32* __restrict__ bitsR) {
  int row = blockIdx.x * 8 + (threadIdx.x >> 6);
  int l = threadIdx.x & 63;
  const int* ap = adj + (size_t)row * NTOT;
  u64* bp = (u64*)(bitsR + (size_t)row * (NTOT / 32));
#pragma unroll 4
  for (int j64 = 0; j64 < NTOT / 64; ++j64) {
    int v = ap[j64 * 64 + l];
    u64 mske = __ballot(v != 0);
    if (l == 0) bp[j64] = mske;
  }
}

// ---------------- k1: h = X @ W  -> h [N][128] f32, hT [128][N] bf16
__global__ __launch_bounds__(256, 2) void k1_project(
    const float* __restrict__ X, const float* __restrict__ W,
    float* __restrict__ h, unsigned short* __restrict__ hT) {
  __shared__ float Xs[32 * 128];            // 16 KB
  __shared__ float Ws[32 * 128];            // 16 KB
  __shared__ unsigned short Hs[128 * 32];   // 8 KB, [o][n]
  int t = threadIdx.x;
  int nb = blockIdx.x * 32;

  const f32x4* Xg = reinterpret_cast<const f32x4*>(X + (size_t)nb * FIN);
  f32x4* Xs4 = reinterpret_cast<f32x4*>(Xs);
#pragma unroll
  for (int r = 0; r < 4; ++r) Xs4[t + r * 256] = Xg[t + r * 256];

  int ng = t >> 5, oq = t & 31;
  int n0 = ng * 4, o0 = oq * 4;
  f32x4 acc[4];
#pragma unroll
  for (int nn = 0; nn < 4; ++nn) acc[nn] = (f32x4){0.f, 0.f, 0.f, 0.f};

  for (int kp = 0; kp < 4; ++kp) {
    __syncthreads();
#pragma unroll
    for (int r = 0; r < 4; ++r) {
      int q = t + r * 256;
      int flat = q * 4;
      int kk = flat >> 7;
      int c = flat & 127;
      int hdd = c >> 5;
      int oo = c & 31;
      *reinterpret_cast<f32x4*>(&Ws[kk * 128 + c]) =
          *reinterpret_cast<const f32x4*>(W + hdd * (FIN * FOUT) +
                                          (kp * 32 + kk) * FOUT + oo);
    }
    __syncthreads();
#pragma unroll 8
    for (int kk = 0; kk < 32; ++kk) {
      f32x4 wv = *reinterpret_cast<const f32x4*>(&Ws[kk * 128 + o0]);
#pragma unroll
      for (int nn = 0; nn < 4; ++nn)
        acc[nn] += Xs[(n0 + nn) * 128 + kp * 32 + kk] * wv;
    }
  }
#pragma unroll
  for (int nn = 0; nn < 4; ++nn) {
    *reinterpret_cast<f32x4*>(&h[(size_t)(nb + n0 + nn) * 128 + o0]) = acc[nn];
#pragma unroll
    for (int c = 0; c < 4; ++c)
      Hs[(o0 + c) * 32 + (n0 + nn)] = f2bf(acc[nn][c]);
  }
  __syncthreads();
  // coalesced hT write: per pass, 16 o-rows x 16 u32 (32 bf16) each
  const u32* Hs32 = reinterpret_cast<const u32*>(Hs);
#pragma unroll
  for (int p = 0; p < 8; ++p) {
    int o = p * 16 + (t >> 4);
    int idx = t & 15;
    reinterpret_cast<u32*>(hT + (size_t)o * NTOT + nb)[idx] = Hs32[o * 16 + idx];
  }
}

// ---------------- k2: per-node scores, pre-scaled by log2(e)
__global__ __launch_bounds__(256, 2) void k2_scores(
    const float* __restrict__ h, const float* __restrict__ a_src,
    const float* __restrict__ a_dst, float* __restrict__ Sl2,
    float* __restrict__ Dl2) {
  int n = blockIdx.x * 256 + threadIdx.x;
  const f32x4* hv = reinterpret_cast<const f32x4*>(h + (size_t)n * 128);
  const f32x4* as4 = reinterpret_cast<const f32x4*>(a_src);
  const f32x4* ad4 = reinterpret_cast<const f32x4*>(a_dst);
#pragma unroll
  for (int hd = 0; hd < NH; ++hd) {
    f32x4 sa = {0.f, 0.f, 0.f, 0.f}, da = {0.f, 0.f, 0.f, 0.f};
#pragma unroll
    for (int q = 0; q < 8; ++q) {
      f32x4 x = hv[hd * 8 + q];
      sa += x * as4[hd * 8 + q];
      da += x * ad4[hd * 8 + q];
    }
    float s = (sa[0] + sa[1]) + (sa[2] + sa[3]);
    float d = (da[0] + da[1]) + (da[2] + da[3]);
    Sl2[hd * NTOT + n] = s * LOG2E;
    Dl2[hd * NTOT + n] = d * LOG2E;
  }
}

// ---------------- k3: fused masked softmax + PV, pipelined, exp2-direct
__global__ __launch_bounds__(512, 4) void k3_attn(
    const u32* __restrict__ bitsR, const float* __restrict__ Sl2,
    const float* __restrict__ Dl2, const unsigned short* __restrict__ hTbits,
    float* __restrict__ pacc, float* __restrict__ plsum) {
  const int N = NTOT;
  int t = threadIdx.x;
  int w = t >> 6;
  int l = t & 63;
  int hd = w & 3;
  int isub = w >> 2;
  int itile = blockIdx.x >> 2;
  int seg = blockIdx.x & 3;
  int ibase = itile * 32 + isub * 16;
  int m = l & 15;
  int i = ibase + m;
  int jc = (l >> 4) * 8;

  float sv = Sl2[hd * N + i];
  const float* dbase = Dl2 + hd * N + seg * SEGJ + jc;
  const u64* bptr =
      reinterpret_cast<const u64*>(bitsR + (size_t)i * (N / 32)) +
      seg * (SEGJ / 64);
  const __bf16* hTg = reinterpret_cast<const __bf16*>(hTbits);
  const __bf16* b0p = hTg + (size_t)(hd * FOUT + m) * N + seg * SEGJ + jc;
  const __bf16* b1p = b0p + (size_t)16 * N;

  f32x4 acc0 = {0.f, 0.f, 0.f, 0.f}, acc1 = {0.f, 0.f, 0.f, 0.f},
        acc2 = {0.f, 0.f, 0.f, 0.f};
  // ones B-fragment: column n==0 all-ones -> row sums in D col 0
  bf16x8 bones;
  {
    u32 pat = (m == 0) ? 0x3f803f80u : 0u;
    u32 tmp[4] = {pat, pat, pat, pat};
    bones = *reinterpret_cast<bf16x8*>(tmp);
  }

#define K3_ISSUE(P, mi_)                                     \
  P##w = bptr[mi_];                                          \
  {                                                          \
    const float* da_ = dbase + (mi_) * 64;                   \
    P##d0 = *reinterpret_cast<const f32x4*>(da_);            \
    P##d1 = *reinterpret_cast<const f32x4*>(da_ + 4);        \
    P##d2 = *reinterpret_cast<const f32x4*>(da_ + 32);       \
    P##d3 = *reinterpret_cast<const f32x4*>(da_ + 36);       \
    const __bf16* b0_ = b0p + (mi_) * 64;                    \
    P##p0 = *reinterpret_cast<const bf16x8*>(b0_);           \
    P##p1 = *reinterpret_cast<const bf16x8*>(b0_ + 32);      \
    const __bf16* b1_ = b1p + (mi_) * 64;                    \
    P##q0 = *reinterpret_cast<const bf16x8*>(b1_);           \
    P##q1 = *reinterpret_cast<const bf16x8*>(b1_ + 32);      \
  }

#define K3_SUB(WW, DA, DB, BP, BQ)                                       \
  {                                                                      \
    unsigned wsh = (WW) >> jc;                                           \
    bf16x8 af;                                                           \
    _Pragma("unroll") for (int e = 0; e < 4; ++e) {                      \
      float x = sv + (DA)[e];                                            \
      float y = (x >= 0.f) ? x : 0.2f * x;                               \
      y = ((wsh >> e) & 1u) ? y : -1e9f;                                 \
      float p;                                                           \
      asm("v_exp_f32 %0, %1" : "=v"(p) : "v"(y));                        \
      af[e] = (__bf16)p;                                                 \
    }                                                                    \
    _Pragma("unroll") for (int e = 0; e < 4; ++e) {                      \
      float x = sv + (DB)[e];                                            \
      float y = (x >= 0.f) ? x : 0.2f * x;                               \
      y = ((wsh >> (e + 4)) & 1u) ? y : -1e9f;                           \
      float p;                                                           \
      asm("v_exp_f32 %0, %1" : "=v"(p) : "v"(y));                        \
      af[e + 4] = (__bf16)p;                                             \
    }                                                                    \
    acc0 = __builtin_amdgcn_mfma_f32_16x16x32_bf16(af, (BP), acc0, 0, 0, 0); \
    acc1 = __builtin_amdgcn_mfma_f32_16x16x32_bf16(af, (BQ), acc1, 0, 0, 0); \
    acc2 = __builtin_amdgcn_mfma_f32_16x16x32_bf16(af, bones, acc2, 0, 0, 0); \
  }

#define K3_COMP(P)                                          \
  K3_SUB((u32)(P##w), P##d0, P##d1, P##p0, P##q0)           \
  K3_SUB((u32)(P##w >> 32), P##d2, P##d3, P##p1, P##q1)

  u64 Aw, Bw;
  f32x4 Ad0, Ad1, Ad2, Ad3, Bd0, Bd1, Bd2, Bd3;
  bf16x8 Ap0, Ap1, Aq0, Aq1, Bp0, Bp1, Bq0, Bq1;

  K3_ISSUE(A, 0)
  K3_ISSUE(B, 1)
#pragma unroll 1
  for (int k = 0; k < 16; ++k) {
    K3_COMP(A)
    K3_ISSUE(A, 2 * k + 2)  // k=15 reads pad region (allocated, unused)
    K3_COMP(B)
    K3_ISSUE(B, 2 * k + 3)
  }
#undef K3_ISSUE
#undef K3_SUB
#undef K3_COMP

  // row sums live in D col 0 (lanes with m==0), rows (l>>4)*4+r
  if (m == 0) {
#pragma unroll
    for (int r = 0; r < 4; ++r)
      plsum[(seg * NH + hd) * N + ibase + ((l >> 4) << 2) + r] = acc2[r];
  }
  // D layout: col=lane&15, row=(lane>>4)*4+reg
#pragma unroll
  for (int half = 0; half < 2; ++half) {
    f32x4 a = half ? acc1 : acc0;
#pragma unroll
    for (int r = 0; r < 4; ++r) {
      int row = ((l >> 4) << 2) + r;
      pacc[((size_t)seg * N + ibase + row) * (NH * FOUT) + hd * FOUT +
           half * 16 + m] = a[r];
    }
  }
}

// ---------------- k4: combine segments + normalize
__global__ __launch_bounds__(256, 2) void k4_combine(
    const float* __restrict__ pacc, const float* __restrict__ plsum,
    float* __restrict__ out) {
  int idx = blockIdx.x * 256 + threadIdx.x;
  int i = idx >> 7;
  int c = idx & 127;
  int hd = c >> 5;
  float a = 0.f, ls = 0.f;
#pragma unroll
  for (int s = 0; s < NSEG; ++s) {
    a += pacc[((size_t)s * NTOT + i) * 128 + c];
    ls += plsum[(s * NH + hd) * NTOT + i];
  }
  out[idx] = (ls > 0.f) ? a / ls : 0.f;
}

extern "C" void kernel_launch(void* const* d_in, const int* in_sizes, int n_in,
                              void* d_out, int out_size, void* d_ws,
                              size_t ws_size, hipStream_t stream) {
  const float* X = (const float*)d_in[0];
  const int* adj = (const int*)d_in[1];
  const float* W = (const float*)d_in[2];
  const float* a_src = (const float*)d_in[3];
  const float* a_dst = (const float*)d_in[4];
  float* out = (float*)d_out;

  char* ws = (char*)d_ws;
  float* h = (float*)(ws + 0x0);                    // 4 MB
  unsigned short* hT = (unsigned short*)(ws + 0x400000);  // 2 MB (+pad)
  float* Sl2 = (float*)(ws + 0x610000);             // 128 KB
  float* Dl2 = (float*)(ws + 0x630000);             // 128 KB (+pad)
  u32* bitsR = (u32*)(ws + 0x660000);               // 8 MB (+pad)
  float* pacc = (float*)(ws + 0xE70000);            // 16 MB
  float* plsum = (float*)(ws + 0x1E70000);          // 512 KB

  k0_pack<<<dim3(1024), dim3(512), 0, stream>>>(adj, bitsR);
  k1_project<<<dim3(256), dim3(256), 0, stream>>>(X, W, h, hT);
  k2_scores<<<dim3(32), dim3(256), 0, stream>>>(h, a_src, a_dst, Sl2, Dl2);
  k3_attn<<<dim3(256 * NSEG), dim3(512), 0, stream>>>(bitsR, Sl2, Dl2,
                                                      (unsigned short*)hT,
                                                      pacc, plsum);
  k4_combine<<<dim3(4096), dim3(256), 0, stream>>>(pacc, plsum, out);
}

// Round 4
// 185.050 us; speedup vs baseline: 2.2820x; 1.4561x over previous
//
#include <hip/hip_runtime.h>
#include <hip/hip_bf16.h>

#define NTOT 8192
#define FIN 128
#define FOUT 32
#define NH 4
#define NSEG 4
#define SEGJ (NTOT / NSEG)  // 2048
#define LOG2E 1.4426950408889634f

typedef __attribute__((ext_vector_type(4))) float f32x4;
typedef __attribute__((ext_vector_type(4))) unsigned int u32x4;
typedef __attribute__((ext_vector_type(8))) __bf16 bf16x8;
typedef unsigned long long u64;
typedef unsigned int u32;

__device__ __forceinline__ unsigned short f2bf(float x) {
  __hip_bfloat16 h = __float2bfloat16(x);
  return *reinterpret_cast<unsigned short*>(&h);
}

__device__ __forceinline__ float fexp2(float y) {
  float p;
  asm("v_exp_f32 %0, %1" : "=v"(p) : "v"(y));
  return p;
}

// ---------------- k0: bit-pack adj -> bits64T[j64][i] (u64 per (row,64j)), 8 MB
__global__ __launch_bounds__(512, 2) void k0_pack(
    const int* __restrict__ adj, u64* __restrict__ bits64T) {
  int row = blockIdx.x * 8 + (threadIdx.x >> 6);
  int l = threadIdx.x & 63;
  const int* ap = adj + (size_t)row * NTOT + l;
  u64* bp = bits64T + row;
#pragma unroll 4
  for (int j64 = 0; j64 < NTOT / 64; ++j64) {
    int v = ap[j64 * 64];
    u64 mske = __ballot(v != 0);
    if (l == 0) bp[(size_t)j64 * NTOT] = mske;
  }
}

// ---------------- k1: h = X @ W -> h [N][128] f32, plus B-fragment panels:
// panel[(p*256 + jt)*512 + l*8 + e] (bf16), p = hd*2+half,
//   value = h[node = jt*32 + (l>>4)*8 + e][p*16 + (l&15)]
__global__ __launch_bounds__(256, 2) void k1_project(
    const float* __restrict__ X, const float* __restrict__ W,
    float* __restrict__ h, unsigned short* __restrict__ panel) {
  __shared__ float Xs[32 * 128];             // 16 KB
  __shared__ float Ws[32 * 128];             // 16 KB
  __shared__ unsigned short Hs[128 * 40];    // 10 KB, [o][node_local], stride 40
  int t = threadIdx.x;
  int nb = blockIdx.x * 32;

  const f32x4* Xg = reinterpret_cast<const f32x4*>(X + (size_t)nb * FIN);
  f32x4* Xs4 = reinterpret_cast<f32x4*>(Xs);
#pragma unroll
  for (int r = 0; r < 4; ++r) Xs4[t + r * 256] = Xg[t + r * 256];

  int ng = t >> 5, oq = t & 31;
  int n0 = ng * 4, o0 = oq * 4;
  f32x4 acc[4];
#pragma unroll
  for (int nn = 0; nn < 4; ++nn) acc[nn] = (f32x4){0.f, 0.f, 0.f, 0.f};

  for (int kp = 0; kp < 4; ++kp) {
    __syncthreads();
#pragma unroll
    for (int r = 0; r < 4; ++r) {
      int q = t + r * 256;
      int flat = q * 4;
      int kk = flat >> 7;
      int c = flat & 127;
      int hdd = c >> 5;
      int oo = c & 31;
      *reinterpret_cast<f32x4*>(&Ws[kk * 128 + c]) =
          *reinterpret_cast<const f32x4*>(W + hdd * (FIN * FOUT) +
                                          (kp * 32 + kk) * FOUT + oo);
    }
    __syncthreads();
#pragma unroll 8
    for (int kk = 0; kk < 32; ++kk) {
      f32x4 wv = *reinterpret_cast<const f32x4*>(&Ws[kk * 128 + o0]);
#pragma unroll
      for (int nn = 0; nn < 4; ++nn)
        acc[nn] += Xs[(n0 + nn) * 128 + kp * 32 + kk] * wv;
    }
  }
#pragma unroll
  for (int nn = 0; nn < 4; ++nn) {
    *reinterpret_cast<f32x4*>(&h[(size_t)(nb + n0 + nn) * 128 + o0]) = acc[nn];
#pragma unroll
    for (int c = 0; c < 4; ++c)
      Hs[(o0 + c) * 40 + (n0 + nn)] = f2bf(acc[nn][c]);
  }
  __syncthreads();
  // panel write: 512 items of 16B; item -> (p = item>>6, l = item&63)
  int jt = blockIdx.x;
#pragma unroll
  for (int it = 0; it < 2; ++it) {
    int item = t + it * 256;
    int p = item >> 6;
    int l = item & 63;
    int o = p * 16 + (l & 15);
    u32x4 v = *reinterpret_cast<const u32x4*>(&Hs[o * 40 + (l >> 4) * 8]);
    *reinterpret_cast<u32x4*>(panel + (size_t)(p * 256 + jt) * 512 + l * 8) = v;
  }
}

// ---------------- k2: per-node scores, pre-scaled by log2(e)
__global__ __launch_bounds__(256, 2) void k2_scores(
    const float* __restrict__ h, const float* __restrict__ a_src,
    const float* __restrict__ a_dst, float* __restrict__ Sl2,
    float* __restrict__ Dl2) {
  int n = blockIdx.x * 256 + threadIdx.x;
  const f32x4* hv = reinterpret_cast<const f32x4*>(h + (size_t)n * 128);
  const f32x4* as4 = reinterpret_cast<const f32x4*>(a_src);
  const f32x4* ad4 = reinterpret_cast<const f32x4*>(a_dst);
#pragma unroll
  for (int hd = 0; hd < NH; ++hd) {
    f32x4 sa = {0.f, 0.f, 0.f, 0.f}, da = {0.f, 0.f, 0.f, 0.f};
#pragma unroll
    for (int q = 0; q < 8; ++q) {
      f32x4 x = hv[hd * 8 + q];
      sa += x * as4[hd * 8 + q];
      da += x * ad4[hd * 8 + q];
    }
    float s = (sa[0] + sa[1]) + (sa[2] + sa[3]);
    float d = (da[0] + da[1]) + (da[2] + da[3]);
    Sl2[hd * NTOT + n] = s * LOG2E;
    Dl2[hd * NTOT + n] = d * LOG2E;
  }
}

// ---------------- k3: fused masked softmax + PV (coalesced panels + bit-LUT)
__global__ __launch_bounds__(512, 4) void k3_attn(
    const u64* __restrict__ bits64T, const float* __restrict__ Sl2,
    const float* __restrict__ Dl2, const unsigned short* __restrict__ panel,
    float* __restrict__ pacc, float* __restrict__ plsum) {
  const int N = NTOT;
  __shared__ u32x4 LUTv[256];  // byte -> 8 halfword masks (4 KB)
  int t = threadIdx.x;
  if (t < 256) {
    u32x4 e;
#pragma unroll
    for (int q = 0; q < 4; ++q)
      e[q] = (((t >> (2 * q)) & 1) ? 0xFFFFu : 0u) |
             (((t >> (2 * q + 1)) & 1) ? 0xFFFF0000u : 0u);
    LUTv[t] = e;
  }
  __syncthreads();

  int w = t >> 6;
  int l = t & 63;
  int hd = w & 3;
  int isub = w >> 2;
  int itile = blockIdx.x >> 2;
  int seg = blockIdx.x & 3;
  int ibase = itile * 32 + isub * 16;
  int m = l & 15;
  int i = ibase + m;
  int jc = (l >> 4) * 8;

  float sv = Sl2[hd * N + i];
  const float* dbase = Dl2 + hd * N + seg * SEGJ + jc;
  const u64* bptr = bits64T + (size_t)(seg * (SEGJ / 64)) * N + i;
  const unsigned short* pan0 =
      panel + (size_t)((hd * 2 + 0) * 256 + seg * (SEGJ / 32)) * 512 + l * 8;
  const unsigned short* pan1 =
      panel + (size_t)((hd * 2 + 1) * 256 + seg * (SEGJ / 32)) * 512 + l * 8;

  f32x4 acc0 = {0.f, 0.f, 0.f, 0.f}, acc1 = {0.f, 0.f, 0.f, 0.f},
        acc2 = {0.f, 0.f, 0.f, 0.f};
  bf16x8 bones;
  {
    u32 pat = (m == 0) ? 0x3f803f80u : 0u;
    u32x4 tmp = {pat, pat, pat, pat};
    bones = *reinterpret_cast<bf16x8*>(&tmp);
  }

#define K3_ISSUE(P, mi_)                                                \
  {                                                                     \
    int mi__ = (mi_) & 31;                                              \
    P##w = bptr[(size_t)mi__ * N];                                      \
    const float* da_ = dbase + mi__ * 64;                               \
    P##d0 = *reinterpret_cast<const f32x4*>(da_);                       \
    P##d1 = *reinterpret_cast<const f32x4*>(da_ + 4);                   \
    P##d2 = *reinterpret_cast<const f32x4*>(da_ + 32);                  \
    P##d3 = *reinterpret_cast<const f32x4*>(da_ + 36);                  \
    const unsigned short* pa_ = pan0 + mi__ * 1024;                     \
    P##p0 = *reinterpret_cast<const bf16x8*>(pa_);                      \
    P##p1 = *reinterpret_cast<const bf16x8*>(pa_ + 512);                \
    const unsigned short* pb_ = pan1 + mi__ * 1024;                     \
    P##q0 = *reinterpret_cast<const bf16x8*>(pb_);                      \
    P##q1 = *reinterpret_cast<const bf16x8*>(pb_ + 512);                \
  }

#define K3_SUB(BY, DA, DB, BP, BQ)                                           \
  {                                                                          \
    u32x4 mk = LUTv[BY];                                                     \
    f32x4 xa = (DA) + sv;                                                    \
    f32x4 xb = (DB) + sv;                                                    \
    f32x4 ya = __builtin_elementwise_max(xa, 0.2f * xa);                     \
    f32x4 yb = __builtin_elementwise_max(xb, 0.2f * xb);                     \
    bf16x8 af;                                                               \
    _Pragma("unroll") for (int e = 0; e < 4; ++e) af[e] =                    \
        (__bf16)fexp2(ya[e]);                                                \
    _Pragma("unroll") for (int e = 0; e < 4; ++e) af[e + 4] =                \
        (__bf16)fexp2(yb[e]);                                                \
    u32x4 afw = *reinterpret_cast<u32x4*>(&af) & mk;                         \
    bf16x8 afm = *reinterpret_cast<bf16x8*>(&afw);                           \
    acc0 = __builtin_amdgcn_mfma_f32_16x16x32_bf16(afm, (BP), acc0, 0, 0, 0); \
    acc1 = __builtin_amdgcn_mfma_f32_16x16x32_bf16(afm, (BQ), acc1, 0, 0, 0); \
    acc2 = __builtin_amdgcn_mfma_f32_16x16x32_bf16(afm, bones, acc2, 0, 0, 0); \
  }

#define K3_COMP(P)                                     \
  {                                                    \
    u32 by0 = ((u32)(P##w >> jc)) & 0xFFu;             \
    u32 by1 = ((u32)((P##w >> 32) >> jc)) & 0xFFu;     \
    K3_SUB(by0, P##d0, P##d1, P##p0, P##q0)            \
    K3_SUB(by1, P##d2, P##d3, P##p1, P##q1)            \
  }

  u64 Aw, Bw;
  f32x4 Ad0, Ad1, Ad2, Ad3, Bd0, Bd1, Bd2, Bd3;
  bf16x8 Ap0, Ap1, Aq0, Aq1, Bp0, Bp1, Bq0, Bq1;

  K3_ISSUE(A, 0)
  K3_ISSUE(B, 1)
#pragma unroll 1
  for (int k = 0; k < 16; ++k) {
    K3_COMP(A)
    K3_ISSUE(A, 2 * k + 2)  // wraps to tile 0 at the tail (harmless reload)
    K3_COMP(B)
    K3_ISSUE(B, 2 * k + 3)
  }
#undef K3_ISSUE
#undef K3_SUB
#undef K3_COMP

  // row sums live in D col 0 (lanes with m==0), rows (l>>4)*4+r
  if (m == 0) {
#pragma unroll
    for (int r = 0; r < 4; ++r)
      plsum[(seg * NH + hd) * N + ibase + ((l >> 4) << 2) + r] = acc2[r];
  }
  // D layout: col=lane&15 (o), row=(lane>>4)*4+reg (i)
#pragma unroll
  for (int half = 0; half < 2; ++half) {
    f32x4 a = half ? acc1 : acc0;
#pragma unroll
    for (int r = 0; r < 4; ++r) {
      int row = ((l >> 4) << 2) + r;
      pacc[((size_t)seg * N + ibase + row) * (NH * FOUT) + hd * FOUT +
           half * 16 + m] = a[r];
    }
  }
}

// ---------------- k4: combine segments + normalize
__global__ __launch_bounds__(256, 2) void k4_combine(
    const float* __restrict__ pacc, const float* __restrict__ plsum,
    float* __restrict__ out) {
  int idx = blockIdx.x * 256 + threadIdx.x;
  int i = idx >> 7;
  int c = idx & 127;
  int hd = c >> 5;
  float a = 0.f, ls = 0.f;
#pragma unroll
  for (int s = 0; s < NSEG; ++s) {
    a += pacc[((size_t)s * NTOT + i) * 128 + c];
    ls += plsum[(s * NH + hd) * NTOT + i];
  }
  out[idx] = (ls > 0.f) ? a / ls : 0.f;
}

extern "C" void kernel_launch(void* const* d_in, const int* in_sizes, int n_in,
                              void* d_out, int out_size, void* d_ws,
                              size_t ws_size, hipStream_t stream) {
  const float* X = (const float*)d_in[0];
  const int* adj = (const int*)d_in[1];
  const float* W = (const float*)d_in[2];
  const float* a_src = (const float*)d_in[3];
  const float* a_dst = (const float*)d_in[4];
  float* out = (float*)d_out;

  char* ws = (char*)d_ws;
  float* h = (float*)(ws + 0x0);                         // 4 MB
  unsigned short* panel = (unsigned short*)(ws + 0x400000);  // 2 MB
  float* Sl2 = (float*)(ws + 0x600000);                  // 128 KB
  float* Dl2 = (float*)(ws + 0x620000);                  // 128 KB
  u64* bits64T = (u64*)(ws + 0x640000);                  // 8 MB
  float* pacc = (float*)(ws + 0xE40000);                 // 16 MB
  float* plsum = (float*)(ws + 0x1E40000);               // 512 KB

  k0_pack<<<dim3(1024), dim3(512), 0, stream>>>(adj, bits64T);
  k1_project<<<dim3(256), dim3(256), 0, stream>>>(X, W, h, panel);
  k2_scores<<<dim3(32), dim3(256), 0, stream>>>(h, a_src, a_dst, Sl2, Dl2);
  k3_attn<<<dim3(256 * NSEG), dim3(512), 0, stream>>>(bits64T, Sl2, Dl2,
                                                      panel, pacc, plsum);
  k4_combine<<<dim3(4096), dim3(256), 0, stream>>>(pacc, plsum, out);
}